// Round 10
// baseline (1020.710 us; speedup 1.0000x reference)
//
#include <hip/hip_runtime.h>
#include <math.h>

// EGCL_Multi on MFMA. Edge kernel: wave-private GEMM rows, acc[16] in AGPRs,
// B staged per-kt via global_load_lds (R8), stage-0 layer-0 computed by MFMA
// (sqn @ We0[0:8] with K zero-padded in the B fragment), mi reduced from live
// accumulators (no LDS round-trip). N=512, NH=8, HD=128, M=256.
#define N_NODES 512
#define NH 8
#define HD 128
#define M 256
#define PITCH 264        // LDS activation row pitch in bf16 (528B)
#define JTILE 64         // edges (j) per block = 4 waves x 16
#define RPW 16           // rows per wave

typedef __bf16 v8bf __attribute__((ext_vector_type(8)));
typedef float f32x4 __attribute__((ext_vector_type(4)));
typedef unsigned short us4v __attribute__((ext_vector_type(4)));

__device__ __forceinline__ float silu_f(float v) { return v / (1.f + __expf(-v)); }
__device__ __forceinline__ unsigned short f2bf(float f) {
  unsigned u = __float_as_uint(f);
  u += 0x7fffu + ((u >> 16) & 1u);
  return (unsigned short)(u >> 16);
}

// async global->LDS, 16B/lane; LDS dest = wave-uniform base + lane*16.
__device__ __forceinline__ void gl2lds16(const unsigned short* g, unsigned short* l) {
  __builtin_amdgcn_global_load_lds(
      (const __attribute__((address_space(1))) unsigned int*)g,
      (__attribute__((address_space(3))) unsigned int*)l, 16, 0, 0);
}

// ---------------------------------------------------------------------------
// Weight prep -> bf16 MFMA-B-fragment order.
// frag[((kt*16+nt)*64+lane)*8+j] = W[kt*32+(lane>>4)*8+j][nt*16+(lane&15)]
// We1 @0, Wx0 @65536, Wx1 @131072, Wxo(256x8 pad16) @196608,
// We0[0:8] (K=8 pad to 32 with zeros, N=256 -> 16 nt tiles) @200704 (8192 shorts).
// ---------------------------------------------------------------------------
__global__ __launch_bounds__(256) void k_prep(
    const float* __restrict__ We0, const float* __restrict__ We1,
    const float* __restrict__ Wx0, const float* __restrict__ Wx1,
    const float* __restrict__ Wxo, unsigned short* __restrict__ wsB)
{
  const int gid = blockIdx.x * 256 + threadIdx.x;
  if (gid >= 208896) return;
  float val;
  if (gid < 196608) {
    const int layer = gid >> 16;
    const int i2 = gid & 65535;
    const int j = i2 & 7, lane = (i2 >> 3) & 63, nt = (i2 >> 9) & 15, kt = i2 >> 13;
    const int k = kt * 32 + (lane >> 4) * 8 + j;
    const int n = nt * 16 + (lane & 15);
    const float* W = (layer == 0) ? We1 : (layer == 1) ? Wx0 : Wx1;
    val = W[k * 256 + n];
  } else if (gid < 200704) {
    const int i2 = gid - 196608;
    const int j = i2 & 7, lane = (i2 >> 3) & 63, kt = (i2 >> 9) & 7;
    const int k = kt * 32 + (lane >> 4) * 8 + j;
    const int n = lane & 15;
    val = (n < 8) ? Wxo[k * 8 + n] : 0.f;
  } else {
    const int i2 = gid - 200704;             // [0,8192): stage-0 We0[0:8] frag
    const int j = i2 & 7, lane = (i2 >> 3) & 63, nt = i2 >> 9;  // nt in [0,16)
    const int quad = lane >> 4, lnib = lane & 15;
    val = (quad == 0) ? We0[j * 256 + nt * 16 + lnib] : 0.f;  // k>=8 rows zero
  }
  wsB[gid] = f2bf(val);
}

// ---------------------------------------------------------------------------
// Per-node P/Q precompute, fp32. Q has be0 pre-folded.
// ---------------------------------------------------------------------------
__global__ __launch_bounds__(256) void k_pq(
    const float* __restrict__ x, const float* __restrict__ h,
    const float* __restrict__ We0, const float* __restrict__ be0,
    float* __restrict__ P, float* __restrict__ Q)
{
  const int i = blockIdx.x, t = threadIdx.x;
  __shared__ float s_x[24];
  __shared__ float s_hc[192];
  if (t < 24) s_x[t] = x[i * 24 + t];
  __syncthreads();
  if (t < HD) {
    s_hc[t] = h[i * HD + t];
  } else if (t < 192) {
    const int p = t - HD, a = p >> 3, b = p & 7;
    float s = 0.f;
#pragma unroll
    for (int d = 0; d < 3; ++d) {
      const float dx = s_x[a * 3 + d] - s_x[b * 3 + d];
      s = fmaf(dx, dx, s);
    }
    s_hc[t] = s;
  }
  __syncthreads();
  float p = 0.f, q = 0.f;
  for (int k = 0; k < 192; ++k) {
    const float hv = s_hc[k];
    p = fmaf(hv, We0[(8 + k) * M + t], p);
    q = fmaf(hv, We0[(200 + k) * M + t], q);
  }
  P[i * M + t] = p;
  Q[i * M + t] = q + be0[t];
}

// ---------------------------------------------------------------------------
// Fused edge pipeline. Block = (i, 64-j tile); wave w owns rows [16w,16w+16).
// ---------------------------------------------------------------------------
__global__ __launch_bounds__(256, 3) void k_edge(
    const float* __restrict__ x,
    const float* __restrict__ P, const float* __restrict__ Q,
    const float* __restrict__ be1,
    const float* __restrict__ Winf, const float* __restrict__ binf,
    const float* __restrict__ bx0, const float* __restrict__ bx1,
    const float* __restrict__ bxo,
    const unsigned short* __restrict__ wsB,
    float* __restrict__ mi_acc, float* __restrict__ shift_acc)
{
  const int i  = blockIdx.x;
  const int j0 = blockIdx.y * JTILE;
  const int t  = threadIdx.x;
  const int lane = t & 63, wave = t >> 6;
  const int lnib = lane & 15, quad = lane >> 4;
  const int r0 = wave * RPW;       // block-local row base
  const int jw = j0 + r0;          // first edge (j) of this wave

  __shared__ __align__(16) unsigned short a_act[JTILE * PITCH];   // 33 KB
  __shared__ __align__(16) unsigned short B_buf[8192];            // 16 KB
  __shared__ __align__(16) float s_sqn[JTILE][8];                 // 2 KB
  __shared__ __align__(16) unsigned short s_sqnb[JTILE][8];       // 1 KB

  // ---- sqn for this wave's 16 rows (fp32 for shift, bf16 for MFMA A) ----
#pragma unroll
  for (int kk = 0; kk < 2; ++kk) {
    const int idx = kk * 64 + lane;          // 0..127 = 16 rows x 8 heads
    const int r = idx >> 3, hh = idx & 7;
    const int j = jw + r;
    float s = 0.f;
#pragma unroll
    for (int d = 0; d < 3; ++d) {
      const float dx = x[j * 24 + hh * 3 + d] - x[i * 24 + hh * 3 + d];
      s = fmaf(dx, dx, s);
    }
    s_sqn[r0 + r][hh] = s;
    s_sqnb[r0 + r][hh] = f2bf(s);
  }

  const float binf0 = binf[0];

  f32x4 acc[16];                             // 64 floats -> AGPRs

  // ---- stage 0 via MFMA: acc = Q'[i] bcast; A = sqn(bf16); B = We0[0:8] ----
  {
#pragma unroll
    for (int nt = 0; nt < 16; ++nt) {
      const float qb = Q[i * M + nt * 16 + lnib];
      acc[nt] = (f32x4){qb, qb, qb, qb};
    }
    const v8bf aS = *(const v8bf*)&s_sqnb[r0 + lnib][0];  // k>=8 garbage, B=0 there
    const unsigned short* B0 = wsB + 200704;
#pragma unroll
    for (int nt = 0; nt < 16; ++nt) {
      const v8bf bv = *(const v8bf*)&B0[(nt * 64 + lane) * 8];
      acc[nt] = __builtin_amdgcn_mfma_f32_16x16x32_bf16(aS, bv, acc[nt], 0, 0, 0);
    }
    // epilogue: add P[j], silu, write a1 (C-layout positions, wave-private rows)
#pragma unroll 4
    for (int nt = 0; nt < 16; ++nt)
#pragma unroll
      for (int reg = 0; reg < 4; ++reg) {
        const int row = r0 + quad * 4 + reg;
        const float pv = P[(j0 + row) * M + nt * 16 + lnib];
        const float v = silu_f(acc[nt][reg] + pv);
        a_act[row * PITCH + nt * 16 + lnib] = f2bf(v);
      }
  }

  // Full 16-nt GEMM over this wave's 16 rows; B staged per-kt through LDS.
  auto run_gemm = [&](const unsigned short* __restrict__ Bg) {
#pragma unroll
    for (int kt = 0; kt < 8; ++kt) {
      __syncthreads();                       // all waves done with prior slice
      {
        const unsigned short* src = Bg + kt * 8192 + wave * 2048 + lane * 8;
        unsigned short* dst = &B_buf[wave * 2048];   // wave-uniform base
        gl2lds16(src,        dst);
        gl2lds16(src + 512,  dst + 512);
        gl2lds16(src + 1024, dst + 1024);
        gl2lds16(src + 1536, dst + 1536);
      }
      __syncthreads();                       // staging complete
      const v8bf a0 = *(const v8bf*)&a_act[(r0 + lnib) * PITCH + kt * 32 + quad * 8];
#pragma unroll
      for (int nt = 0; nt < 16; ++nt) {
        const v8bf bv = *(const v8bf*)&B_buf[nt * 512 + lane * 8];
        acc[nt] = __builtin_amdgcn_mfma_f32_16x16x32_bf16(a0, bv, acc[nt], 0, 0, 0);
      }
    }
  };

  // ===== GEMM1: m = silu(a1 @ We1 + be1), diag mask, gate, mi — all in-reg =====
#pragma unroll
  for (int nt = 0; nt < 16; ++nt) {
    const float b = be1[nt * 16 + lnib];
    acc[nt] = (f32x4){b, b, b, b};
  }
  run_gemm(wsB);
  {
    float ge[4] = {0.f, 0.f, 0.f, 0.f};
#pragma unroll
    for (int nt = 0; nt < 16; ++nt) {
      const float wfv = Winf[nt * 16 + lnib];
#pragma unroll
      for (int reg = 0; reg < 4; ++reg) {
        float v = silu_f(acc[nt][reg]);
        const int row = r0 + quad * 4 + reg;
        if (j0 + row == i) v = 0.f;
        a_act[row * PITCH + nt * 16 + lnib] = f2bf(v);
        ge[reg] = fmaf(v, wfv, ge[reg]);
        acc[nt][reg] = v;                    // keep fp32 m for mi
      }
    }
    float ev[4];
#pragma unroll
    for (int reg = 0; reg < 4; ++reg) {
      float g = ge[reg];
      g += __shfl_xor(g, 1);
      g += __shfl_xor(g, 2);
      g += __shfl_xor(g, 4);
      g += __shfl_xor(g, 8);
      ev[reg] = 1.f / (1.f + __expf(-(g + binf0)));   // e for row quad*4+reg
    }
    // mi[col] partial over this wave's 16 rows: in-reg + cross-quad butterfly
#pragma unroll
    for (int nt = 0; nt < 16; ++nt) {
      float p = acc[nt][0] * ev[0];
      p = fmaf(acc[nt][1], ev[1], p);
      p = fmaf(acc[nt][2], ev[2], p);
      p = fmaf(acc[nt][3], ev[3], p);
      p += __shfl_xor(p, 16);
      p += __shfl_xor(p, 32);
      if (quad == 0) atomicAdd(&mi_acc[i * M + nt * 16 + lnib], p);
    }
  }

  // ===== GEMM2: a2 = silu(m @ Wx0 + bx0) =====
#pragma unroll
  for (int nt = 0; nt < 16; ++nt) {
    const float b = bx0[nt * 16 + lnib];
    acc[nt] = (f32x4){b, b, b, b};
  }
  run_gemm(wsB + 65536);
#pragma unroll
  for (int nt = 0; nt < 16; ++nt)
#pragma unroll
    for (int reg = 0; reg < 4; ++reg) {
      const int row = r0 + quad * 4 + reg;
      a_act[row * PITCH + nt * 16 + lnib] = f2bf(silu_f(acc[nt][reg]));
    }

  // ===== GEMM3: a3 = silu(a2 @ Wx1 + bx1) =====
#pragma unroll
  for (int nt = 0; nt < 16; ++nt) {
    const float b = bx1[nt * 16 + lnib];
    acc[nt] = (f32x4){b, b, b, b};
  }
  run_gemm(wsB + 131072);
#pragma unroll
  for (int nt = 0; nt < 16; ++nt)
#pragma unroll
    for (int reg = 0; reg < 4; ++reg) {
      const int row = r0 + quad * 4 + reg;
      a_act[row * PITCH + nt * 16 + lnib] = f2bf(silu_f(acc[nt][reg]));
    }

  // ===== GEMM4: px = a3 @ Wxo + bxo (N padded to 16; cols 8..15 zero) =====
  f32x4 px;
  {
    const float b = (lnib < 8) ? bxo[lnib] : 0.f;
    px = (f32x4){b, b, b, b};
    const unsigned short* B = wsB + 196608;
#pragma unroll
    for (int kt = 0; kt < 8; ++kt) {
      const v8bf a0 = *(const v8bf*)&a_act[(r0 + lnib) * PITCH + kt * 32 + quad * 8];
      const v8bf bv = *(const v8bf*)&B[(kt * 64 + lane) * 8];
      px = __builtin_amdgcn_mfma_f32_16x16x32_bf16(a0, bv, px, 0, 0, 0);
    }
  }

  // ===== shift: per-head normalized coordinate aggregation (wave-local) =====
  {
    const int hh = lnib & 7;   // lanes lnib>=8 hold zero px (padded B cols)
    const float xi0 = x[i * 24 + hh * 3 + 0];
    const float xi1 = x[i * 24 + hh * 3 + 1];
    const float xi2 = x[i * 24 + hh * 3 + 2];
    float p0 = 0.f, p1 = 0.f, p2 = 0.f;
#pragma unroll
    for (int reg = 0; reg < 4; ++reg) {
      const int row = r0 + quad * 4 + reg;
      const int jg = j0 + row;
      if (jg != i) {
        const float pxv = px[reg];
        const float sq  = s_sqn[row][hh];
        const float f   = pxv / (sqrtf(sq + 1e-8f) + 1.f);  // NORM_CONST=1
        p0 = fmaf(x[jg * 24 + hh * 3 + 0] - xi0, f, p0);
        p1 = fmaf(x[jg * 24 + hh * 3 + 1] - xi1, f, p1);
        p2 = fmaf(x[jg * 24 + hh * 3 + 2] - xi2, f, p2);
      }
    }
    p0 += __shfl_xor(p0, 16); p0 += __shfl_xor(p0, 32);
    p1 += __shfl_xor(p1, 16); p1 += __shfl_xor(p1, 32);
    p2 += __shfl_xor(p2, 16); p2 += __shfl_xor(p2, 32);
    if (lane < 8) {
      atomicAdd(&shift_acc[i * 24 + hh * 3 + 0], p0);
      atomicAdd(&shift_acc[i * 24 + hh * 3 + 1], p1);
      atomicAdd(&shift_acc[i * 24 + hh * 3 + 2], p2);
    }
  }
}

// ---------------------------------------------------------------------------
__global__ void k_xout(const float* __restrict__ x, const float* __restrict__ shift,
                       float* __restrict__ out)
{
  const int idx = blockIdx.x * 256 + threadIdx.x;
  if (idx < N_NODES * NH * 3) out[idx] = x[idx] + shift[idx] * (1.f / 511.f);
}

__global__ __launch_bounds__(256) void k_hout(
    const float* __restrict__ h, const float* __restrict__ mi,
    const float* __restrict__ Wh0, const float* __restrict__ bh0,
    const float* __restrict__ Wh1, const float* __restrict__ bh1,
    const float* __restrict__ Who, const float* __restrict__ bho,
    float* __restrict__ out)
{
  const int i = blockIdx.x, t = threadIdx.x;
  __shared__ float s_in[M + HD];
  __shared__ float s_b[M];
  s_in[t] = mi[i * M + t];
  if (t < HD) s_in[M + t] = h[i * HD + t];
  __syncthreads();
  float acc = bh0[t];
  for (int k = 0; k < M + HD; ++k) acc = fmaf(s_in[k], Wh0[k * M + t], acc);
  s_b[t] = silu_f(acc);
  __syncthreads();
  float acc2 = bh1[t];
  for (int k = 0; k < M; ++k) acc2 = fmaf(s_b[k], Wh1[k * M + t], acc2);
  const float a1v = silu_f(acc2);
  __syncthreads();
  s_in[t] = a1v;
  __syncthreads();
  if (t < HD) {
    float o = bho[t];
    for (int k = 0; k < M; ++k) o = fmaf(s_in[k], Who[k * HD + t], o);
    out[i * HD + t] = h[i * HD + t] + o;
  }
}

// ---------------------------------------------------------------------------
extern "C" void kernel_launch(void* const* d_in, const int* in_sizes, int n_in,
                              void* d_out, int out_size, void* d_ws, size_t ws_size,
                              hipStream_t stream)
{
  const float* x    = (const float*)d_in[0];
  const float* h    = (const float*)d_in[1];
  const float* We0  = (const float*)d_in[2];
  const float* be0  = (const float*)d_in[3];
  const float* We1  = (const float*)d_in[4];
  const float* be1  = (const float*)d_in[5];
  const float* Winf = (const float*)d_in[6];
  const float* binf = (const float*)d_in[7];
  const float* Wx0  = (const float*)d_in[8];
  const float* bx0  = (const float*)d_in[9];
  const float* Wx1  = (const float*)d_in[10];
  const float* bx1  = (const float*)d_in[11];
  const float* Wxo  = (const float*)d_in[12];
  const float* bxo  = (const float*)d_in[13];
  const float* Wh0  = (const float*)d_in[14];
  const float* bh0  = (const float*)d_in[15];
  const float* Wh1  = (const float*)d_in[16];
  const float* bh1  = (const float*)d_in[17];
  const float* Who  = (const float*)d_in[18];
  const float* bho  = (const float*)d_in[19];

  float* out_x = (float*)d_out;                 // [512,8,3]
  float* out_h = out_x + N_NODES * NH * 3;      // [512,128]

  // ws layout (float units): mi[131072] | shift[12288] | P[131072] | Q[131072] | wsB(bf16)
  float* ws    = (float*)d_ws;
  float* mi    = ws;
  float* shift = ws + 131072;
  float* P     = ws + 143360;
  float* Q     = ws + 274432;
  unsigned short* wsB = (unsigned short*)(ws + 405504);

  hipMemsetAsync(mi, 0, (131072 + 12288) * sizeof(float), stream);

  k_prep<<<816, 256, 0, stream>>>(We0, We1, Wx0, Wx1, Wxo, wsB);
  k_pq<<<N_NODES, 256, 0, stream>>>(x, h, We0, be0, P, Q);
  k_edge<<<dim3(N_NODES, N_NODES / JTILE), 256, 0, stream>>>(
      x, P, Q, be1, Winf, binf, bx0, bx1, bxo, wsB, mi, shift);
  k_xout<<<(N_NODES * NH * 3 + 255) / 256, 256, 0, stream>>>(x, shift, out_x);
  k_hout<<<N_NODES, 256, 0, stream>>>(h, mi, Wh0, bh0, Wh1, bh1, Who, bho, out_h);
}

// Round 11
// 359.083 us; speedup vs baseline: 2.8425x; 2.8425x over previous
//
#include <hip/hip_runtime.h>
#include <math.h>

// EGCL_Multi on MFMA. R8 structure (wave-private rows, acc[16] AGPR, B staged
// per-kt via global_load_lds, mi via LDS re-read) + stage-0 on MFMA with
// spill-safe ordering: acc init = P loads (acc otherwise dead), 16 MFMAs,
// epilogue adds Q only. N=512, NH=8, HD=128, M=256.
#define N_NODES 512
#define NH 8
#define HD 128
#define M 256
#define PITCH 264        // LDS activation row pitch in bf16 (528B)
#define JTILE 64         // edges (j) per block = 4 waves x 16
#define RPW 16           // rows per wave

typedef __bf16 v8bf __attribute__((ext_vector_type(8)));
typedef float f32x4 __attribute__((ext_vector_type(4)));
typedef unsigned short us4v __attribute__((ext_vector_type(4)));

__device__ __forceinline__ float silu_f(float v) { return v / (1.f + __expf(-v)); }
__device__ __forceinline__ unsigned short f2bf(float f) {
  unsigned u = __float_as_uint(f);
  u += 0x7fffu + ((u >> 16) & 1u);
  return (unsigned short)(u >> 16);
}
__device__ __forceinline__ float bf2f(unsigned short s) {
  return __uint_as_float(((unsigned)s) << 16);
}

// async global->LDS, 16B/lane; LDS dest = wave-uniform base + lane*16.
__device__ __forceinline__ void gl2lds16(const unsigned short* g, unsigned short* l) {
  __builtin_amdgcn_global_load_lds(
      (const __attribute__((address_space(1))) unsigned int*)g,
      (__attribute__((address_space(3))) unsigned int*)l, 16, 0, 0);
}

// ---------------------------------------------------------------------------
// Weight prep -> bf16 MFMA-B-fragment order.
// frag[((kt*16+nt)*64+lane)*8+j] = W[kt*32+(lane>>4)*8+j][nt*16+(lane&15)]
// We1 @0, Wx0 @65536, Wx1 @131072, Wxo(256x8 pad16) @196608,
// We0[0:8] (K=8 pad to 32 with zeros, 16 nt tiles) @200704 (8192 shorts).
// ---------------------------------------------------------------------------
__global__ __launch_bounds__(256) void k_prep(
    const float* __restrict__ We0, const float* __restrict__ We1,
    const float* __restrict__ Wx0, const float* __restrict__ Wx1,
    const float* __restrict__ Wxo, unsigned short* __restrict__ wsB)
{
  const int gid = blockIdx.x * 256 + threadIdx.x;
  if (gid >= 208896) return;
  float val;
  if (gid < 196608) {
    const int layer = gid >> 16;
    const int i2 = gid & 65535;
    const int j = i2 & 7, lane = (i2 >> 3) & 63, nt = (i2 >> 9) & 15, kt = i2 >> 13;
    const int k = kt * 32 + (lane >> 4) * 8 + j;
    const int n = nt * 16 + (lane & 15);
    const float* W = (layer == 0) ? We1 : (layer == 1) ? Wx0 : Wx1;
    val = W[k * 256 + n];
  } else if (gid < 200704) {
    const int i2 = gid - 196608;
    const int j = i2 & 7, lane = (i2 >> 3) & 63, kt = (i2 >> 9) & 7;
    const int k = kt * 32 + (lane >> 4) * 8 + j;
    const int n = lane & 15;
    val = (n < 8) ? Wxo[k * 8 + n] : 0.f;
  } else {
    const int i2 = gid - 200704;             // [0,8192): stage-0 We0[0:8] frag
    const int j = i2 & 7, lane = (i2 >> 3) & 63, nt = i2 >> 9;  // nt in [0,16)
    const int quad = lane >> 4, lnib = lane & 15;
    val = (quad == 0) ? We0[j * 256 + nt * 16 + lnib] : 0.f;  // k>=8 rows zero
  }
  wsB[gid] = f2bf(val);
}

// ---------------------------------------------------------------------------
// Per-node P/Q precompute, fp32. Q has be0 pre-folded.
// ---------------------------------------------------------------------------
__global__ __launch_bounds__(256) void k_pq(
    const float* __restrict__ x, const float* __restrict__ h,
    const float* __restrict__ We0, const float* __restrict__ be0,
    float* __restrict__ P, float* __restrict__ Q)
{
  const int i = blockIdx.x, t = threadIdx.x;
  __shared__ float s_x[24];
  __shared__ float s_hc[192];
  if (t < 24) s_x[t] = x[i * 24 + t];
  __syncthreads();
  if (t < HD) {
    s_hc[t] = h[i * HD + t];
  } else if (t < 192) {
    const int p = t - HD, a = p >> 3, b = p & 7;
    float s = 0.f;
#pragma unroll
    for (int d = 0; d < 3; ++d) {
      const float dx = s_x[a * 3 + d] - s_x[b * 3 + d];
      s = fmaf(dx, dx, s);
    }
    s_hc[t] = s;
  }
  __syncthreads();
  float p = 0.f, q = 0.f;
  for (int k = 0; k < 192; ++k) {
    const float hv = s_hc[k];
    p = fmaf(hv, We0[(8 + k) * M + t], p);
    q = fmaf(hv, We0[(200 + k) * M + t], q);
  }
  P[i * M + t] = p;
  Q[i * M + t] = q + be0[t];
}

// ---------------------------------------------------------------------------
// Fused edge pipeline. Block = (i, 64-j tile); wave w owns rows [16w,16w+16).
// ---------------------------------------------------------------------------
__global__ __launch_bounds__(256, 3) void k_edge(
    const float* __restrict__ x,
    const float* __restrict__ P, const float* __restrict__ Q,
    const float* __restrict__ be1,
    const float* __restrict__ Winf, const float* __restrict__ binf,
    const float* __restrict__ bx0, const float* __restrict__ bx1,
    const float* __restrict__ bxo,
    const unsigned short* __restrict__ wsB,
    float* __restrict__ mi_acc, float* __restrict__ shift_acc)
{
  const int i  = blockIdx.x;
  const int j0 = blockIdx.y * JTILE;
  const int t  = threadIdx.x;
  const int lane = t & 63, wave = t >> 6;
  const int lnib = lane & 15, quad = lane >> 4;
  const int r0 = wave * RPW;       // block-local row base
  const int jw = j0 + r0;          // first edge (j) of this wave

  __shared__ __align__(16) unsigned short a_act[JTILE * PITCH];   // 33 KB
  __shared__ __align__(16) unsigned short B_buf[8192];            // 16 KB
  __shared__ __align__(16) float s_sqn[JTILE][8];                 // 2 KB
  __shared__ __align__(16) unsigned short s_sqnb[JTILE][8];       // 1 KB
  __shared__ float s_e[JTILE];                                    // 256 B

  // ---- sqn for this wave's 16 rows (fp32 for shift, bf16 for MFMA A) ----
#pragma unroll
  for (int kk = 0; kk < 2; ++kk) {
    const int idx = kk * 64 + lane;          // 0..127 = 16 rows x 8 heads
    const int r = idx >> 3, hh = idx & 7;
    const int j = jw + r;
    float s = 0.f;
#pragma unroll
    for (int d = 0; d < 3; ++d) {
      const float dx = x[j * 24 + hh * 3 + d] - x[i * 24 + hh * 3 + d];
      s = fmaf(dx, dx, s);
    }
    s_sqn[r0 + r][hh] = s;
    s_sqnb[r0 + r][hh] = f2bf(s);
  }

  const float binf0 = binf[0];

  f32x4 acc[16];                             // 64 floats -> AGPRs

  // ---- stage 0 via MFMA: acc init = P[j-row][col] (acc dead before this,
  //      loads complete before MFMA); A = sqn bf16 (k>=8 garbage, B rows 0);
  //      epilogue adds Q'[i][col] (16 scalar loads only) + silu -> a_act ----
  {
#pragma unroll
    for (int nt = 0; nt < 16; ++nt)
#pragma unroll
      for (int reg = 0; reg < 4; ++reg)
        acc[nt][reg] = P[(jw + quad * 4 + reg) * M + nt * 16 + lnib];
    const v8bf aS = *(const v8bf*)&s_sqnb[r0 + lnib][0];
    const unsigned short* B0 = wsB + 200704;
#pragma unroll
    for (int nt = 0; nt < 16; ++nt) {
      const v8bf bv = *(const v8bf*)&B0[(nt * 64 + lane) * 8];
      acc[nt] = __builtin_amdgcn_mfma_f32_16x16x32_bf16(aS, bv, acc[nt], 0, 0, 0);
    }
#pragma unroll
    for (int nt = 0; nt < 16; ++nt) {
      const float qv = Q[i * M + nt * 16 + lnib];
#pragma unroll
      for (int reg = 0; reg < 4; ++reg) {
        const int row = r0 + quad * 4 + reg;
        a_act[row * PITCH + nt * 16 + lnib] = f2bf(silu_f(acc[nt][reg] + qv));
      }
    }
  }

  // Full 16-nt GEMM over this wave's 16 rows; B staged per-kt through LDS.
  auto run_gemm = [&](const unsigned short* __restrict__ Bg) {
#pragma unroll
    for (int kt = 0; kt < 8; ++kt) {
      __syncthreads();                       // all waves done with prior slice
      {
        const unsigned short* src = Bg + kt * 8192 + wave * 2048 + lane * 8;
        unsigned short* dst = &B_buf[wave * 2048];   // wave-uniform base
        gl2lds16(src,        dst);
        gl2lds16(src + 512,  dst + 512);
        gl2lds16(src + 1024, dst + 1024);
        gl2lds16(src + 1536, dst + 1536);
      }
      __syncthreads();                       // staging complete
      const v8bf a0 = *(const v8bf*)&a_act[(r0 + lnib) * PITCH + kt * 32 + quad * 8];
#pragma unroll
      for (int nt = 0; nt < 16; ++nt) {
        const v8bf bv = *(const v8bf*)&B_buf[nt * 512 + lane * 8];
        acc[nt] = __builtin_amdgcn_mfma_f32_16x16x32_bf16(a0, bv, acc[nt], 0, 0, 0);
      }
    }
  };

  // ===== GEMM1: m = silu(a1 @ We1 + be1), diag mask, gate =====
#pragma unroll
  for (int nt = 0; nt < 16; ++nt) {
    const float b = be1[nt * 16 + lnib];
    acc[nt] = (f32x4){b, b, b, b};
  }
  run_gemm(wsB);
  {
    float ge[4] = {0.f, 0.f, 0.f, 0.f};
#pragma unroll
    for (int nt = 0; nt < 16; ++nt) {
      const float wfv = Winf[nt * 16 + lnib];
#pragma unroll
      for (int reg = 0; reg < 4; ++reg) {
        float v = silu_f(acc[nt][reg]);
        const int row = r0 + quad * 4 + reg;
        if (j0 + row == i) v = 0.f;
        a_act[row * PITCH + nt * 16 + lnib] = f2bf(v);
        ge[reg] = fmaf(v, wfv, ge[reg]);
      }
    }
#pragma unroll
    for (int reg = 0; reg < 4; ++reg) {
      float g = ge[reg];
      g += __shfl_xor(g, 1);
      g += __shfl_xor(g, 2);
      g += __shfl_xor(g, 4);
      g += __shfl_xor(g, 8);
      const float ev = 1.f / (1.f + __expf(-(g + binf0)));
      if (lnib == 0) s_e[r0 + quad * 4 + reg] = ev;
    }
  }

  // ===== mi: wave-private LDS re-read of m, scaled by e[r] =====
  {
    const int c0 = lane * 4;
    f32x4 mip = (f32x4){0.f, 0.f, 0.f, 0.f};
#pragma unroll
    for (int r = 0; r < RPW; ++r) {
      const us4v mv = *(const us4v*)&a_act[(r0 + r) * PITCH + c0];
      const float ev = s_e[r0 + r];          // broadcast
      mip[0] = fmaf(bf2f(mv[0]), ev, mip[0]);
      mip[1] = fmaf(bf2f(mv[1]), ev, mip[1]);
      mip[2] = fmaf(bf2f(mv[2]), ev, mip[2]);
      mip[3] = fmaf(bf2f(mv[3]), ev, mip[3]);
    }
    atomicAdd(&mi_acc[i * M + c0 + 0], mip[0]);
    atomicAdd(&mi_acc[i * M + c0 + 1], mip[1]);
    atomicAdd(&mi_acc[i * M + c0 + 2], mip[2]);
    atomicAdd(&mi_acc[i * M + c0 + 3], mip[3]);
  }

  // ===== GEMM2: a2 = silu(m @ Wx0 + bx0) =====
#pragma unroll
  for (int nt = 0; nt < 16; ++nt) {
    const float b = bx0[nt * 16 + lnib];
    acc[nt] = (f32x4){b, b, b, b};
  }
  run_gemm(wsB + 65536);
#pragma unroll
  for (int nt = 0; nt < 16; ++nt)
#pragma unroll
    for (int reg = 0; reg < 4; ++reg) {
      const int row = r0 + quad * 4 + reg;
      a_act[row * PITCH + nt * 16 + lnib] = f2bf(silu_f(acc[nt][reg]));
    }

  // ===== GEMM3: a3 = silu(a2 @ Wx1 + bx1) =====
#pragma unroll
  for (int nt = 0; nt < 16; ++nt) {
    const float b = bx1[nt * 16 + lnib];
    acc[nt] = (f32x4){b, b, b, b};
  }
  run_gemm(wsB + 131072);
#pragma unroll
  for (int nt = 0; nt < 16; ++nt)
#pragma unroll
    for (int reg = 0; reg < 4; ++reg) {
      const int row = r0 + quad * 4 + reg;
      a_act[row * PITCH + nt * 16 + lnib] = f2bf(silu_f(acc[nt][reg]));
    }

  // ===== GEMM4: px = a3 @ Wxo + bxo (N padded to 16; cols 8..15 zero) =====
  f32x4 px;
  {
    const float b = (lnib < 8) ? bxo[lnib] : 0.f;
    px = (f32x4){b, b, b, b};
    const unsigned short* B = wsB + 196608;
#pragma unroll
    for (int kt = 0; kt < 8; ++kt) {
      const v8bf a0 = *(const v8bf*)&a_act[(r0 + lnib) * PITCH + kt * 32 + quad * 8];
      const v8bf bv = *(const v8bf*)&B[(kt * 64 + lane) * 8];
      px = __builtin_amdgcn_mfma_f32_16x16x32_bf16(a0, bv, px, 0, 0, 0);
    }
  }

  // ===== shift: per-head normalized coordinate aggregation (wave-local) =====
  {
    const int hh = lnib & 7;   // lanes lnib>=8 hold zero px (padded B cols)
    const float xi0 = x[i * 24 + hh * 3 + 0];
    const float xi1 = x[i * 24 + hh * 3 + 1];
    const float xi2 = x[i * 24 + hh * 3 + 2];
    float p0 = 0.f, p1 = 0.f, p2 = 0.f;
#pragma unroll
    for (int reg = 0; reg < 4; ++reg) {
      const int row = r0 + quad * 4 + reg;
      const int jg = j0 + row;
      if (jg != i) {
        const float pxv = px[reg];
        const float sq  = s_sqn[row][hh];
        const float f   = pxv / (sqrtf(sq + 1e-8f) + 1.f);  // NORM_CONST=1
        p0 = fmaf(x[jg * 24 + hh * 3 + 0] - xi0, f, p0);
        p1 = fmaf(x[jg * 24 + hh * 3 + 1] - xi1, f, p1);
        p2 = fmaf(x[jg * 24 + hh * 3 + 2] - xi2, f, p2);
      }
    }
    p0 += __shfl_xor(p0, 16); p0 += __shfl_xor(p0, 32);
    p1 += __shfl_xor(p1, 16); p1 += __shfl_xor(p1, 32);
    p2 += __shfl_xor(p2, 16); p2 += __shfl_xor(p2, 32);
    if (lane < 8) {
      atomicAdd(&shift_acc[i * 24 + hh * 3 + 0], p0);
      atomicAdd(&shift_acc[i * 24 + hh * 3 + 1], p1);
      atomicAdd(&shift_acc[i * 24 + hh * 3 + 2], p2);
    }
  }
}

// ---------------------------------------------------------------------------
__global__ void k_xout(const float* __restrict__ x, const float* __restrict__ shift,
                       float* __restrict__ out)
{
  const int idx = blockIdx.x * 256 + threadIdx.x;
  if (idx < N_NODES * NH * 3) out[idx] = x[idx] + shift[idx] * (1.f / 511.f);
}

__global__ __launch_bounds__(256) void k_hout(
    const float* __restrict__ h, const float* __restrict__ mi,
    const float* __restrict__ Wh0, const float* __restrict__ bh0,
    const float* __restrict__ Wh1, const float* __restrict__ bh1,
    const float* __restrict__ Who, const float* __restrict__ bho,
    float* __restrict__ out)
{
  const int i = blockIdx.x, t = threadIdx.x;
  __shared__ float s_in[M + HD];
  __shared__ float s_b[M];
  s_in[t] = mi[i * M + t];
  if (t < HD) s_in[M + t] = h[i * HD + t];
  __syncthreads();
  float acc = bh0[t];
  for (int k = 0; k < M + HD; ++k) acc = fmaf(s_in[k], Wh0[k * M + t], acc);
  s_b[t] = silu_f(acc);
  __syncthreads();
  float acc2 = bh1[t];
  for (int k = 0; k < M; ++k) acc2 = fmaf(s_b[k], Wh1[k * M + t], acc2);
  const float a1v = silu_f(acc2);
  __syncthreads();
  s_in[t] = a1v;
  __syncthreads();
  if (t < HD) {
    float o = bho[t];
    for (int k = 0; k < M; ++k) o = fmaf(s_in[k], Who[k * HD + t], o);
    out[i * HD + t] = h[i * HD + t] + o;
  }
}

// ---------------------------------------------------------------------------
extern "C" void kernel_launch(void* const* d_in, const int* in_sizes, int n_in,
                              void* d_out, int out_size, void* d_ws, size_t ws_size,
                              hipStream_t stream)
{
  const float* x    = (const float*)d_in[0];
  const float* h    = (const float*)d_in[1];
  const float* We0  = (const float*)d_in[2];
  const float* be0  = (const float*)d_in[3];
  const float* We1  = (const float*)d_in[4];
  const float* be1  = (const float*)d_in[5];
  const float* Winf = (const float*)d_in[6];
  const float* binf = (const float*)d_in[7];
  const float* Wx0  = (const float*)d_in[8];
  const float* bx0  = (const float*)d_in[9];
  const float* Wx1  = (const float*)d_in[10];
  const float* bx1  = (const float*)d_in[11];
  const float* Wxo  = (const float*)d_in[12];
  const float* bxo  = (const float*)d_in[13];
  const float* Wh0  = (const float*)d_in[14];
  const float* bh0  = (const float*)d_in[15];
  const float* Wh1  = (const float*)d_in[16];
  const float* bh1  = (const float*)d_in[17];
  const float* Who  = (const float*)d_in[18];
  const float* bho  = (const float*)d_in[19];

  float* out_x = (float*)d_out;                 // [512,8,3]
  float* out_h = out_x + N_NODES * NH * 3;      // [512,128]

  // ws layout (float units): mi[131072] | shift[12288] | P[131072] | Q[131072] | wsB(bf16)
  float* ws    = (float*)d_ws;
  float* mi    = ws;
  float* shift = ws + 131072;
  float* P     = ws + 143360;
  float* Q     = ws + 274432;
  unsigned short* wsB = (unsigned short*)(ws + 405504);

  hipMemsetAsync(mi, 0, (131072 + 12288) * sizeof(float), stream);

  k_prep<<<816, 256, 0, stream>>>(We0, We1, Wx0, Wx1, Wxo, wsB);
  k_pq<<<N_NODES, 256, 0, stream>>>(x, h, We0, be0, P, Q);
  k_edge<<<dim3(N_NODES, N_NODES / JTILE), 256, 0, stream>>>(
      x, P, Q, be1, Winf, binf, bx0, bx1, bxo, wsB, mi, shift);
  k_xout<<<(N_NODES * NH * 3 + 255) / 256, 256, 0, stream>>>(x, shift, out_x);
  k_hout<<<N_NODES, 256, 0, stream>>>(h, mi, Wh0, bh0, Wh1, bh1, Who, bho, out_h);
}

// Round 12
// 345.270 us; speedup vs baseline: 2.9563x; 1.0400x over previous
//
#include <hip/hip_runtime.h>
#include <math.h>

// EGCL_Multi on MFMA. R11 structure + cheap bf16 pack (d16_hi stores) and
// kernel fusion (prep+pq+zeroing fused; xout folded into hout; no memset).
// N=512, NH=8, HD=128, M=256.
#define N_NODES 512
#define NH 8
#define HD 128
#define M 256
#define PITCH 264        // LDS activation row pitch in bf16 (528B)
#define JTILE 64         // edges (j) per block = 4 waves x 16
#define RPW 16           // rows per wave

typedef __bf16 v8bf __attribute__((ext_vector_type(8)));
typedef float f32x4 __attribute__((ext_vector_type(4)));
typedef unsigned short us4v __attribute__((ext_vector_type(4)));

__device__ __forceinline__ float silu_f(float v) { return v / (1.f + __expf(-v)); }
// RNE (used for weight prep only)
__device__ __forceinline__ unsigned short f2bf(float f) {
  unsigned u = __float_as_uint(f);
  u += 0x7fffu + ((u >> 16) & 1u);
  return (unsigned short)(u >> 16);
}
// cheap half-up rounding: 1 VALU op + d16_hi store pattern
__device__ __forceinline__ unsigned short f2bf_hi(float f) {
  return (unsigned short)((__float_as_uint(f) + 0x8000u) >> 16);
}
__device__ __forceinline__ float bf2f(unsigned short s) {
  return __uint_as_float(((unsigned)s) << 16);
}

// async global->LDS, 16B/lane; LDS dest = wave-uniform base + lane*16.
__device__ __forceinline__ void gl2lds16(const unsigned short* g, unsigned short* l) {
  __builtin_amdgcn_global_load_lds(
      (const __attribute__((address_space(1))) unsigned int*)g,
      (__attribute__((address_space(3))) unsigned int*)l, 16, 0, 0);
}

// ---------------------------------------------------------------------------
// Fused prep (blocks 0..815) + per-node P/Q & accumulator zeroing (816..1327).
// Weight frag layout: frag[((kt*16+nt)*64+lane)*8+j] =
//   W[kt*32+(lane>>4)*8+j][nt*16+(lane&15)]
// We1 @0, Wx0 @65536, Wx1 @131072, Wxo(256x8 pad16) @196608,
// We0[0:8] (K=8 pad 32, 16 nt tiles) @200704 (8192 shorts).
// ---------------------------------------------------------------------------
__global__ __launch_bounds__(256) void k_pre(
    const float* __restrict__ x, const float* __restrict__ h,
    const float* __restrict__ We0, const float* __restrict__ be0,
    const float* __restrict__ We1, const float* __restrict__ Wx0,
    const float* __restrict__ Wx1, const float* __restrict__ Wxo,
    unsigned short* __restrict__ wsB,
    float* __restrict__ P, float* __restrict__ Q,
    float* __restrict__ mi, float* __restrict__ shift)
{
  const int t = threadIdx.x;
  if (blockIdx.x < 816) {
    const int gid = blockIdx.x * 256 + t;
    if (gid >= 208896) return;
    float val;
    if (gid < 196608) {
      const int layer = gid >> 16;
      const int i2 = gid & 65535;
      const int j = i2 & 7, lane = (i2 >> 3) & 63, nt = (i2 >> 9) & 15, kt = i2 >> 13;
      const int k = kt * 32 + (lane >> 4) * 8 + j;
      const int n = nt * 16 + (lane & 15);
      const float* W = (layer == 0) ? We1 : (layer == 1) ? Wx0 : Wx1;
      val = W[k * 256 + n];
    } else if (gid < 200704) {
      const int i2 = gid - 196608;
      const int j = i2 & 7, lane = (i2 >> 3) & 63, kt = (i2 >> 9) & 7;
      const int k = kt * 32 + (lane >> 4) * 8 + j;
      const int n = lane & 15;
      val = (n < 8) ? Wxo[k * 8 + n] : 0.f;
    } else {
      const int i2 = gid - 200704;           // [0,8192): stage-0 We0[0:8] frag
      const int j = i2 & 7, lane = (i2 >> 3) & 63, nt = i2 >> 9;
      const int quad = lane >> 4, lnib = lane & 15;
      val = (quad == 0) ? We0[j * 256 + nt * 16 + lnib] : 0.f;
    }
    wsB[gid] = f2bf(val);
    return;
  }
  // ---- P/Q branch ----
  const int i = blockIdx.x - 816;
  __shared__ float s_x[24];
  __shared__ float s_hc[192];
  // zero accumulators (replaces memset)
  mi[i * M + t] = 0.f;
  if (t < 24) { shift[i * 24 + t] = 0.f; s_x[t] = x[i * 24 + t]; }
  __syncthreads();
  if (t < HD) {
    s_hc[t] = h[i * HD + t];
  } else if (t < 192) {
    const int p = t - HD, a = p >> 3, b = p & 7;
    float s = 0.f;
#pragma unroll
    for (int d = 0; d < 3; ++d) {
      const float dx = s_x[a * 3 + d] - s_x[b * 3 + d];
      s = fmaf(dx, dx, s);
    }
    s_hc[t] = s;
  }
  __syncthreads();
  float p = 0.f, q = 0.f;
  for (int k = 0; k < 192; ++k) {
    const float hv = s_hc[k];
    p = fmaf(hv, We0[(8 + k) * M + t], p);
    q = fmaf(hv, We0[(200 + k) * M + t], q);
  }
  P[i * M + t] = p;
  Q[i * M + t] = q + be0[t];               // be0 folded
}

// ---------------------------------------------------------------------------
// Fused edge pipeline. Block = (i, 64-j tile); wave w owns rows [16w,16w+16).
// ---------------------------------------------------------------------------
__global__ __launch_bounds__(256, 3) void k_edge(
    const float* __restrict__ x,
    const float* __restrict__ P, const float* __restrict__ Q,
    const float* __restrict__ be1,
    const float* __restrict__ Winf, const float* __restrict__ binf,
    const float* __restrict__ bx0, const float* __restrict__ bx1,
    const float* __restrict__ bxo,
    const unsigned short* __restrict__ wsB,
    float* __restrict__ mi_acc, float* __restrict__ shift_acc)
{
  const int i  = blockIdx.x;
  const int j0 = blockIdx.y * JTILE;
  const int t  = threadIdx.x;
  const int lane = t & 63, wave = t >> 6;
  const int lnib = lane & 15, quad = lane >> 4;
  const int r0 = wave * RPW;       // block-local row base
  const int jw = j0 + r0;          // first edge (j) of this wave

  __shared__ __align__(16) unsigned short a_act[JTILE * PITCH];   // 33 KB
  __shared__ __align__(16) unsigned short B_buf[8192];            // 16 KB
  __shared__ __align__(16) float s_sqn[JTILE][8];                 // 2 KB
  __shared__ __align__(16) unsigned short s_sqnb[JTILE][8];       // 1 KB
  __shared__ float s_e[JTILE];                                    // 256 B

  // ---- sqn for this wave's 16 rows (fp32 for shift, bf16 for MFMA A) ----
#pragma unroll
  for (int kk = 0; kk < 2; ++kk) {
    const int idx = kk * 64 + lane;          // 0..127 = 16 rows x 8 heads
    const int r = idx >> 3, hh = idx & 7;
    const int j = jw + r;
    float s = 0.f;
#pragma unroll
    for (int d = 0; d < 3; ++d) {
      const float dx = x[j * 24 + hh * 3 + d] - x[i * 24 + hh * 3 + d];
      s = fmaf(dx, dx, s);
    }
    s_sqn[r0 + r][hh] = s;
    s_sqnb[r0 + r][hh] = f2bf(s);
  }

  const float binf0 = binf[0];

  f32x4 acc[16];                             // 64 floats -> AGPRs

  // ---- stage 0 via MFMA: acc init = P[j-row][col] (acc dead before this);
  //      A = sqn bf16 (k>=8 garbage, B rows 0); epilogue adds Q'[i] + silu ----
  {
#pragma unroll
    for (int nt = 0; nt < 16; ++nt)
#pragma unroll
      for (int reg = 0; reg < 4; ++reg)
        acc[nt][reg] = P[(jw + quad * 4 + reg) * M + nt * 16 + lnib];
    const v8bf aS = *(const v8bf*)&s_sqnb[r0 + lnib][0];
    const unsigned short* B0 = wsB + 200704;
#pragma unroll
    for (int nt = 0; nt < 16; ++nt) {
      const v8bf bv = *(const v8bf*)&B0[(nt * 64 + lane) * 8];
      acc[nt] = __builtin_amdgcn_mfma_f32_16x16x32_bf16(aS, bv, acc[nt], 0, 0, 0);
    }
#pragma unroll
    for (int nt = 0; nt < 16; ++nt) {
      const float qv = Q[i * M + nt * 16 + lnib];
#pragma unroll
      for (int reg = 0; reg < 4; ++reg) {
        const int row = r0 + quad * 4 + reg;
        a_act[row * PITCH + nt * 16 + lnib] = f2bf_hi(silu_f(acc[nt][reg] + qv));
      }
    }
  }

  // Full 16-nt GEMM over this wave's 16 rows; B staged per-kt through LDS.
  auto run_gemm = [&](const unsigned short* __restrict__ Bg) {
#pragma unroll
    for (int kt = 0; kt < 8; ++kt) {
      __syncthreads();                       // all waves done with prior slice
      {
        const unsigned short* src = Bg + kt * 8192 + wave * 2048 + lane * 8;
        unsigned short* dst = &B_buf[wave * 2048];   // wave-uniform base
        gl2lds16(src,        dst);
        gl2lds16(src + 512,  dst + 512);
        gl2lds16(src + 1024, dst + 1024);
        gl2lds16(src + 1536, dst + 1536);
      }
      __syncthreads();                       // staging complete
      const v8bf a0 = *(const v8bf*)&a_act[(r0 + lnib) * PITCH + kt * 32 + quad * 8];
#pragma unroll
      for (int nt = 0; nt < 16; ++nt) {
        const v8bf bv = *(const v8bf*)&B_buf[nt * 512 + lane * 8];
        acc[nt] = __builtin_amdgcn_mfma_f32_16x16x32_bf16(a0, bv, acc[nt], 0, 0, 0);
      }
    }
  };

  // ===== GEMM1: m = silu(a1 @ We1 + be1), diag mask, gate =====
#pragma unroll
  for (int nt = 0; nt < 16; ++nt) {
    const float b = be1[nt * 16 + lnib];
    acc[nt] = (f32x4){b, b, b, b};
  }
  run_gemm(wsB);
  {
    float ge[4] = {0.f, 0.f, 0.f, 0.f};
#pragma unroll
    for (int nt = 0; nt < 16; ++nt) {
      const float wfv = Winf[nt * 16 + lnib];
#pragma unroll
      for (int reg = 0; reg < 4; ++reg) {
        float v = silu_f(acc[nt][reg]);
        const int row = r0 + quad * 4 + reg;
        if (j0 + row == i) v = 0.f;
        a_act[row * PITCH + nt * 16 + lnib] = f2bf_hi(v);
        ge[reg] = fmaf(v, wfv, ge[reg]);
      }
    }
#pragma unroll
    for (int reg = 0; reg < 4; ++reg) {
      float g = ge[reg];
      g += __shfl_xor(g, 1);
      g += __shfl_xor(g, 2);
      g += __shfl_xor(g, 4);
      g += __shfl_xor(g, 8);
      const float ev = 1.f / (1.f + __expf(-(g + binf0)));
      if (lnib == 0) s_e[r0 + quad * 4 + reg] = ev;
    }
  }

  // ===== mi: wave-private LDS re-read of m, scaled by e[r] =====
  {
    const int c0 = lane * 4;
    f32x4 mip = (f32x4){0.f, 0.f, 0.f, 0.f};
#pragma unroll
    for (int r = 0; r < RPW; ++r) {
      const us4v mv = *(const us4v*)&a_act[(r0 + r) * PITCH + c0];
      const float ev = s_e[r0 + r];          // broadcast
      mip[0] = fmaf(bf2f(mv[0]), ev, mip[0]);
      mip[1] = fmaf(bf2f(mv[1]), ev, mip[1]);
      mip[2] = fmaf(bf2f(mv[2]), ev, mip[2]);
      mip[3] = fmaf(bf2f(mv[3]), ev, mip[3]);
    }
    atomicAdd(&mi_acc[i * M + c0 + 0], mip[0]);
    atomicAdd(&mi_acc[i * M + c0 + 1], mip[1]);
    atomicAdd(&mi_acc[i * M + c0 + 2], mip[2]);
    atomicAdd(&mi_acc[i * M + c0 + 3], mip[3]);
  }

  // ===== GEMM2: a2 = silu(m @ Wx0 + bx0) =====
#pragma unroll
  for (int nt = 0; nt < 16; ++nt) {
    const float b = bx0[nt * 16 + lnib];
    acc[nt] = (f32x4){b, b, b, b};
  }
  run_gemm(wsB + 65536);
#pragma unroll
  for (int nt = 0; nt < 16; ++nt)
#pragma unroll
    for (int reg = 0; reg < 4; ++reg) {
      const int row = r0 + quad * 4 + reg;
      a_act[row * PITCH + nt * 16 + lnib] = f2bf_hi(silu_f(acc[nt][reg]));
    }

  // ===== GEMM3: a3 = silu(a2 @ Wx1 + bx1) =====
#pragma unroll
  for (int nt = 0; nt < 16; ++nt) {
    const float b = bx1[nt * 16 + lnib];
    acc[nt] = (f32x4){b, b, b, b};
  }
  run_gemm(wsB + 131072);
#pragma unroll
  for (int nt = 0; nt < 16; ++nt)
#pragma unroll
    for (int reg = 0; reg < 4; ++reg) {
      const int row = r0 + quad * 4 + reg;
      a_act[row * PITCH + nt * 16 + lnib] = f2bf_hi(silu_f(acc[nt][reg]));
    }

  // ===== GEMM4: px = a3 @ Wxo + bxo (N padded to 16; cols 8..15 zero) =====
  f32x4 px;
  {
    const float b = (lnib < 8) ? bxo[lnib] : 0.f;
    px = (f32x4){b, b, b, b};
    const unsigned short* B = wsB + 196608;
#pragma unroll
    for (int kt = 0; kt < 8; ++kt) {
      const v8bf a0 = *(const v8bf*)&a_act[(r0 + lnib) * PITCH + kt * 32 + quad * 8];
      const v8bf bv = *(const v8bf*)&B[(kt * 64 + lane) * 8];
      px = __builtin_amdgcn_mfma_f32_16x16x32_bf16(a0, bv, px, 0, 0, 0);
    }
  }

  // ===== shift: per-head normalized coordinate aggregation (wave-local) =====
  {
    const int hh = lnib & 7;   // lanes lnib>=8 hold zero px (padded B cols)
    const float xi0 = x[i * 24 + hh * 3 + 0];
    const float xi1 = x[i * 24 + hh * 3 + 1];
    const float xi2 = x[i * 24 + hh * 3 + 2];
    float p0 = 0.f, p1 = 0.f, p2 = 0.f;
#pragma unroll
    for (int reg = 0; reg < 4; ++reg) {
      const int row = r0 + quad * 4 + reg;
      const int jg = j0 + row;
      if (jg != i) {
        const float pxv = px[reg];
        const float sq  = s_sqn[row][hh];
        const float f   = pxv / (sqrtf(sq + 1e-8f) + 1.f);  // NORM_CONST=1
        p0 = fmaf(x[jg * 24 + hh * 3 + 0] - xi0, f, p0);
        p1 = fmaf(x[jg * 24 + hh * 3 + 1] - xi1, f, p1);
        p2 = fmaf(x[jg * 24 + hh * 3 + 2] - xi2, f, p2);
      }
    }
    p0 += __shfl_xor(p0, 16); p0 += __shfl_xor(p0, 32);
    p1 += __shfl_xor(p1, 16); p1 += __shfl_xor(p1, 32);
    p2 += __shfl_xor(p2, 16); p2 += __shfl_xor(p2, 32);
    if (lane < 8) {
      atomicAdd(&shift_acc[i * 24 + hh * 3 + 0], p0);
      atomicAdd(&shift_acc[i * 24 + hh * 3 + 1], p1);
      atomicAdd(&shift_acc[i * 24 + hh * 3 + 2], p2);
    }
  }
}

// ---------------------------------------------------------------------------
// h-output (phi_h MLP + residual) with x-output folded in (threads t<24).
// ---------------------------------------------------------------------------
__global__ __launch_bounds__(256) void k_hout(
    const float* __restrict__ x, const float* __restrict__ shift,
    const float* __restrict__ h, const float* __restrict__ mi,
    const float* __restrict__ Wh0, const float* __restrict__ bh0,
    const float* __restrict__ Wh1, const float* __restrict__ bh1,
    const float* __restrict__ Who, const float* __restrict__ bho,
    float* __restrict__ out_x, float* __restrict__ out_h)
{
  const int i = blockIdx.x, t = threadIdx.x;
  __shared__ float s_in[M + HD];
  __shared__ float s_b[M];
  if (t < 24) out_x[i * 24 + t] = x[i * 24 + t] + shift[i * 24 + t] * (1.f / 511.f);
  s_in[t] = mi[i * M + t];
  if (t < HD) s_in[M + t] = h[i * HD + t];
  __syncthreads();
  float acc = bh0[t];
  for (int k = 0; k < M + HD; ++k) acc = fmaf(s_in[k], Wh0[k * M + t], acc);
  s_b[t] = silu_f(acc);
  __syncthreads();
  float acc2 = bh1[t];
  for (int k = 0; k < M; ++k) acc2 = fmaf(s_b[k], Wh1[k * M + t], acc2);
  const float a1v = silu_f(acc2);
  __syncthreads();
  s_in[t] = a1v;
  __syncthreads();
  if (t < HD) {
    float o = bho[t];
    for (int k = 0; k < M; ++k) o = fmaf(s_in[k], Who[k * HD + t], o);
    out_h[i * HD + t] = h[i * HD + t] + o;
  }
}

// ---------------------------------------------------------------------------
extern "C" void kernel_launch(void* const* d_in, const int* in_sizes, int n_in,
                              void* d_out, int out_size, void* d_ws, size_t ws_size,
                              hipStream_t stream)
{
  const float* x    = (const float*)d_in[0];
  const float* h    = (const float*)d_in[1];
  const float* We0  = (const float*)d_in[2];
  const float* be0  = (const float*)d_in[3];
  const float* We1  = (const float*)d_in[4];
  const float* be1  = (const float*)d_in[5];
  const float* Winf = (const float*)d_in[6];
  const float* binf = (const float*)d_in[7];
  const float* Wx0  = (const float*)d_in[8];
  const float* bx0  = (const float*)d_in[9];
  const float* Wx1  = (const float*)d_in[10];
  const float* bx1  = (const float*)d_in[11];
  const float* Wxo  = (const float*)d_in[12];
  const float* bxo  = (const float*)d_in[13];
  const float* Wh0  = (const float*)d_in[14];
  const float* bh0  = (const float*)d_in[15];
  const float* Wh1  = (const float*)d_in[16];
  const float* bh1  = (const float*)d_in[17];
  const float* Who  = (const float*)d_in[18];
  const float* bho  = (const float*)d_in[19];

  float* out_x = (float*)d_out;                 // [512,8,3]
  float* out_h = out_x + N_NODES * NH * 3;      // [512,128]

  // ws layout (float units): mi[131072] | shift[12288] | P[131072] | Q[131072] | wsB(bf16)
  float* ws    = (float*)d_ws;
  float* mi    = ws;
  float* shift = ws + 131072;
  float* P     = ws + 143360;
  float* Q     = ws + 274432;
  unsigned short* wsB = (unsigned short*)(ws + 405504);

  k_pre<<<816 + N_NODES, 256, 0, stream>>>(
      x, h, We0, be0, We1, Wx0, Wx1, Wxo, wsB, P, Q, mi, shift);
  k_edge<<<dim3(N_NODES, N_NODES / JTILE), 256, 0, stream>>>(
      x, P, Q, be1, Winf, binf, bx0, bx1, bxo, wsB, mi, shift);
  k_hout<<<N_NODES, 256, 0, stream>>>(
      x, shift, h, mi, Wh0, bh0, Wh1, bh1, Who, bho, out_x, out_h);
}

// Round 13
// 316.836 us; speedup vs baseline: 3.2216x; 1.0897x over previous
//
#include <hip/hip_runtime.h>
#include <math.h>

// EGCL_Multi on MFMA. R12 structure + fast-math rcp for silu/sigmoid
// (no -ffast-math in harness: precise fp32 div was ~10 VALU insts each;
// outputs quantize to bf16 so 1-ulp v_rcp_f32 is exact enough).
// N=512, NH=8, HD=128, M=256.
#define N_NODES 512
#define NH 8
#define HD 128
#define M 256
#define PITCH 264        // LDS activation row pitch in bf16 (528B)
#define JTILE 64         // edges (j) per block = 4 waves x 16
#define RPW 16           // rows per wave

typedef __bf16 v8bf __attribute__((ext_vector_type(8)));
typedef float f32x4 __attribute__((ext_vector_type(4)));
typedef unsigned short us4v __attribute__((ext_vector_type(4)));

__device__ __forceinline__ float silu_f(float v) {
  return v * __builtin_amdgcn_rcpf(1.f + __expf(-v));
}
__device__ __forceinline__ float sigmoid_f(float v) {
  return __builtin_amdgcn_rcpf(1.f + __expf(-v));
}
// RNE (weight prep only)
__device__ __forceinline__ unsigned short f2bf(float f) {
  unsigned u = __float_as_uint(f);
  u += 0x7fffu + ((u >> 16) & 1u);
  return (unsigned short)(u >> 16);
}
// cheap half-up rounding (epilogue stores)
__device__ __forceinline__ unsigned short f2bf_hi(float f) {
  return (unsigned short)((__float_as_uint(f) + 0x8000u) >> 16);
}
__device__ __forceinline__ float bf2f(unsigned short s) {
  return __uint_as_float(((unsigned)s) << 16);
}

// async global->LDS, 16B/lane; LDS dest = wave-uniform base + lane*16.
__device__ __forceinline__ void gl2lds16(const unsigned short* g, unsigned short* l) {
  __builtin_amdgcn_global_load_lds(
      (const __attribute__((address_space(1))) unsigned int*)g,
      (__attribute__((address_space(3))) unsigned int*)l, 16, 0, 0);
}

// ---------------------------------------------------------------------------
// Fused prep (blocks 0..815) + per-node P/Q & accumulator zeroing (816..1327).
// Weight frag layout: frag[((kt*16+nt)*64+lane)*8+j] =
//   W[kt*32+(lane>>4)*8+j][nt*16+(lane&15)]
// We1 @0, Wx0 @65536, Wx1 @131072, Wxo(256x8 pad16) @196608,
// We0[0:8] (K=8 pad 32, 16 nt tiles) @200704 (8192 shorts).
// ---------------------------------------------------------------------------
__global__ __launch_bounds__(256) void k_pre(
    const float* __restrict__ x, const float* __restrict__ h,
    const float* __restrict__ We0, const float* __restrict__ be0,
    const float* __restrict__ We1, const float* __restrict__ Wx0,
    const float* __restrict__ Wx1, const float* __restrict__ Wxo,
    unsigned short* __restrict__ wsB,
    float* __restrict__ P, float* __restrict__ Q,
    float* __restrict__ mi, float* __restrict__ shift)
{
  const int t = threadIdx.x;
  if (blockIdx.x < 816) {
    const int gid = blockIdx.x * 256 + t;
    if (gid >= 208896) return;
    float val;
    if (gid < 196608) {
      const int layer = gid >> 16;
      const int i2 = gid & 65535;
      const int j = i2 & 7, lane = (i2 >> 3) & 63, nt = (i2 >> 9) & 15, kt = i2 >> 13;
      const int k = kt * 32 + (lane >> 4) * 8 + j;
      const int n = nt * 16 + (lane & 15);
      const float* W = (layer == 0) ? We1 : (layer == 1) ? Wx0 : Wx1;
      val = W[k * 256 + n];
    } else if (gid < 200704) {
      const int i2 = gid - 196608;
      const int j = i2 & 7, lane = (i2 >> 3) & 63, kt = (i2 >> 9) & 7;
      const int k = kt * 32 + (lane >> 4) * 8 + j;
      const int n = lane & 15;
      val = (n < 8) ? Wxo[k * 8 + n] : 0.f;
    } else {
      const int i2 = gid - 200704;           // [0,8192): stage-0 We0[0:8] frag
      const int j = i2 & 7, lane = (i2 >> 3) & 63, nt = i2 >> 9;
      const int quad = lane >> 4, lnib = lane & 15;
      val = (quad == 0) ? We0[j * 256 + nt * 16 + lnib] : 0.f;
    }
    wsB[gid] = f2bf(val);
    return;
  }
  // ---- P/Q branch ----
  const int i = blockIdx.x - 816;
  __shared__ float s_x[24];
  __shared__ float s_hc[192];
  // zero accumulators (replaces memset)
  mi[i * M + t] = 0.f;
  if (t < 24) { shift[i * 24 + t] = 0.f; s_x[t] = x[i * 24 + t]; }
  __syncthreads();
  if (t < HD) {
    s_hc[t] = h[i * HD + t];
  } else if (t < 192) {
    const int p = t - HD, a = p >> 3, b = p & 7;
    float s = 0.f;
#pragma unroll
    for (int d = 0; d < 3; ++d) {
      const float dx = s_x[a * 3 + d] - s_x[b * 3 + d];
      s = fmaf(dx, dx, s);
    }
    s_hc[t] = s;
  }
  __syncthreads();
  float p = 0.f, q = 0.f;
  for (int k = 0; k < 192; ++k) {
    const float hv = s_hc[k];
    p = fmaf(hv, We0[(8 + k) * M + t], p);
    q = fmaf(hv, We0[(200 + k) * M + t], q);
  }
  P[i * M + t] = p;
  Q[i * M + t] = q + be0[t];               // be0 folded
}

// ---------------------------------------------------------------------------
// Fused edge pipeline. Block = (i, 64-j tile); wave w owns rows [16w,16w+16).
// ---------------------------------------------------------------------------
__global__ __launch_bounds__(256, 3) void k_edge(
    const float* __restrict__ x,
    const float* __restrict__ P, const float* __restrict__ Q,
    const float* __restrict__ be1,
    const float* __restrict__ Winf, const float* __restrict__ binf,
    const float* __restrict__ bx0, const float* __restrict__ bx1,
    const float* __restrict__ bxo,
    const unsigned short* __restrict__ wsB,
    float* __restrict__ mi_acc, float* __restrict__ shift_acc)
{
  const int i  = blockIdx.x;
  const int j0 = blockIdx.y * JTILE;
  const int t  = threadIdx.x;
  const int lane = t & 63, wave = t >> 6;
  const int lnib = lane & 15, quad = lane >> 4;
  const int r0 = wave * RPW;       // block-local row base
  const int jw = j0 + r0;          // first edge (j) of this wave

  __shared__ __align__(16) unsigned short a_act[JTILE * PITCH];   // 33 KB
  __shared__ __align__(16) unsigned short B_buf[8192];            // 16 KB
  __shared__ __align__(16) float s_sqn[JTILE][8];                 // 2 KB
  __shared__ __align__(16) unsigned short s_sqnb[JTILE][8];       // 1 KB
  __shared__ float s_e[JTILE];                                    // 256 B

  // ---- sqn for this wave's 16 rows (fp32 for shift, bf16 for MFMA A) ----
#pragma unroll
  for (int kk = 0; kk < 2; ++kk) {
    const int idx = kk * 64 + lane;          // 0..127 = 16 rows x 8 heads
    const int r = idx >> 3, hh = idx & 7;
    const int j = jw + r;
    float s = 0.f;
#pragma unroll
    for (int d = 0; d < 3; ++d) {
      const float dx = x[j * 24 + hh * 3 + d] - x[i * 24 + hh * 3 + d];
      s = fmaf(dx, dx, s);
    }
    s_sqn[r0 + r][hh] = s;
    s_sqnb[r0 + r][hh] = f2bf(s);
  }

  const float binf0 = binf[0];

  f32x4 acc[16];                             // 64 floats -> AGPRs

  // ---- stage 0 via MFMA: acc init = P[j-row][col] (acc dead before this);
  //      A = sqn bf16 (k>=8 garbage, B rows 0); epilogue adds Q'[i] + silu ----
  {
#pragma unroll
    for (int nt = 0; nt < 16; ++nt)
#pragma unroll
      for (int reg = 0; reg < 4; ++reg)
        acc[nt][reg] = P[(jw + quad * 4 + reg) * M + nt * 16 + lnib];
    const v8bf aS = *(const v8bf*)&s_sqnb[r0 + lnib][0];
    const unsigned short* B0 = wsB + 200704;
#pragma unroll
    for (int nt = 0; nt < 16; ++nt) {
      const v8bf bv = *(const v8bf*)&B0[(nt * 64 + lane) * 8];
      acc[nt] = __builtin_amdgcn_mfma_f32_16x16x32_bf16(aS, bv, acc[nt], 0, 0, 0);
    }
#pragma unroll
    for (int nt = 0; nt < 16; ++nt) {
      const float qv = Q[i * M + nt * 16 + lnib];
#pragma unroll
      for (int reg = 0; reg < 4; ++reg) {
        const int row = r0 + quad * 4 + reg;
        a_act[row * PITCH + nt * 16 + lnib] = f2bf_hi(silu_f(acc[nt][reg] + qv));
      }
    }
  }

  // Full 16-nt GEMM over this wave's 16 rows; B staged per-kt through LDS.
  auto run_gemm = [&](const unsigned short* __restrict__ Bg) {
#pragma unroll
    for (int kt = 0; kt < 8; ++kt) {
      __syncthreads();                       // all waves done with prior slice
      {
        const unsigned short* src = Bg + kt * 8192 + wave * 2048 + lane * 8;
        unsigned short* dst = &B_buf[wave * 2048];   // wave-uniform base
        gl2lds16(src,        dst);
        gl2lds16(src + 512,  dst + 512);
        gl2lds16(src + 1024, dst + 1024);
        gl2lds16(src + 1536, dst + 1536);
      }
      __syncthreads();                       // staging complete
      const v8bf a0 = *(const v8bf*)&a_act[(r0 + lnib) * PITCH + kt * 32 + quad * 8];
#pragma unroll
      for (int nt = 0; nt < 16; ++nt) {
        const v8bf bv = *(const v8bf*)&B_buf[nt * 512 + lane * 8];
        acc[nt] = __builtin_amdgcn_mfma_f32_16x16x32_bf16(a0, bv, acc[nt], 0, 0, 0);
      }
    }
  };

  // ===== GEMM1: m = silu(a1 @ We1 + be1), diag mask, gate =====
#pragma unroll
  for (int nt = 0; nt < 16; ++nt) {
    const float b = be1[nt * 16 + lnib];
    acc[nt] = (f32x4){b, b, b, b};
  }
  run_gemm(wsB);
  {
    float ge[4] = {0.f, 0.f, 0.f, 0.f};
#pragma unroll
    for (int nt = 0; nt < 16; ++nt) {
      const float wfv = Winf[nt * 16 + lnib];
#pragma unroll
      for (int reg = 0; reg < 4; ++reg) {
        float v = silu_f(acc[nt][reg]);
        const int row = r0 + quad * 4 + reg;
        if (j0 + row == i) v = 0.f;
        a_act[row * PITCH + nt * 16 + lnib] = f2bf_hi(v);
        ge[reg] = fmaf(v, wfv, ge[reg]);
      }
    }
#pragma unroll
    for (int reg = 0; reg < 4; ++reg) {
      float g = ge[reg];
      g += __shfl_xor(g, 1);
      g += __shfl_xor(g, 2);
      g += __shfl_xor(g, 4);
      g += __shfl_xor(g, 8);
      const float ev = sigmoid_f(g + binf0);
      if (lnib == 0) s_e[r0 + quad * 4 + reg] = ev;
    }
  }

  // ===== mi: wave-private LDS re-read of m, scaled by e[r] =====
  {
    const int c0 = lane * 4;
    f32x4 mip = (f32x4){0.f, 0.f, 0.f, 0.f};
#pragma unroll
    for (int r = 0; r < RPW; ++r) {
      const us4v mv = *(const us4v*)&a_act[(r0 + r) * PITCH + c0];
      const float ev = s_e[r0 + r];          // broadcast
      mip[0] = fmaf(bf2f(mv[0]), ev, mip[0]);
      mip[1] = fmaf(bf2f(mv[1]), ev, mip[1]);
      mip[2] = fmaf(bf2f(mv[2]), ev, mip[2]);
      mip[3] = fmaf(bf2f(mv[3]), ev, mip[3]);
    }
    atomicAdd(&mi_acc[i * M + c0 + 0], mip[0]);
    atomicAdd(&mi_acc[i * M + c0 + 1], mip[1]);
    atomicAdd(&mi_acc[i * M + c0 + 2], mip[2]);
    atomicAdd(&mi_acc[i * M + c0 + 3], mip[3]);
  }

  // ===== GEMM2: a2 = silu(m @ Wx0 + bx0) =====
#pragma unroll
  for (int nt = 0; nt < 16; ++nt) {
    const float b = bx0[nt * 16 + lnib];
    acc[nt] = (f32x4){b, b, b, b};
  }
  run_gemm(wsB + 65536);
#pragma unroll
  for (int nt = 0; nt < 16; ++nt)
#pragma unroll
    for (int reg = 0; reg < 4; ++reg) {
      const int row = r0 + quad * 4 + reg;
      a_act[row * PITCH + nt * 16 + lnib] = f2bf_hi(silu_f(acc[nt][reg]));
    }

  // ===== GEMM3: a3 = silu(a2 @ Wx1 + bx1) =====
#pragma unroll
  for (int nt = 0; nt < 16; ++nt) {
    const float b = bx1[nt * 16 + lnib];
    acc[nt] = (f32x4){b, b, b, b};
  }
  run_gemm(wsB + 131072);
#pragma unroll
  for (int nt = 0; nt < 16; ++nt)
#pragma unroll
    for (int reg = 0; reg < 4; ++reg) {
      const int row = r0 + quad * 4 + reg;
      a_act[row * PITCH + nt * 16 + lnib] = f2bf_hi(silu_f(acc[nt][reg]));
    }

  // ===== GEMM4: px = a3 @ Wxo + bxo (N padded to 16; cols 8..15 zero) =====
  f32x4 px;
  {
    const float b = (lnib < 8) ? bxo[lnib] : 0.f;
    px = (f32x4){b, b, b, b};
    const unsigned short* B = wsB + 196608;
#pragma unroll
    for (int kt = 0; kt < 8; ++kt) {
      const v8bf a0 = *(const v8bf*)&a_act[(r0 + lnib) * PITCH + kt * 32 + quad * 8];
      const v8bf bv = *(const v8bf*)&B[(kt * 64 + lane) * 8];
      px = __builtin_amdgcn_mfma_f32_16x16x32_bf16(a0, bv, px, 0, 0, 0);
    }
  }

  // ===== shift: per-head normalized coordinate aggregation (wave-local) =====
  {
    const int hh = lnib & 7;   // lanes lnib>=8 hold zero px (padded B cols)
    const float xi0 = x[i * 24 + hh * 3 + 0];
    const float xi1 = x[i * 24 + hh * 3 + 1];
    const float xi2 = x[i * 24 + hh * 3 + 2];
    float p0 = 0.f, p1 = 0.f, p2 = 0.f;
#pragma unroll
    for (int reg = 0; reg < 4; ++reg) {
      const int row = r0 + quad * 4 + reg;
      const int jg = j0 + row;
      if (jg != i) {
        const float pxv = px[reg];
        const float sq  = s_sqn[row][hh];
        const float f   = pxv * __builtin_amdgcn_rcpf(sqrtf(sq + 1e-8f) + 1.f);
        p0 = fmaf(x[jg * 24 + hh * 3 + 0] - xi0, f, p0);
        p1 = fmaf(x[jg * 24 + hh * 3 + 1] - xi1, f, p1);
        p2 = fmaf(x[jg * 24 + hh * 3 + 2] - xi2, f, p2);
      }
    }
    p0 += __shfl_xor(p0, 16); p0 += __shfl_xor(p0, 32);
    p1 += __shfl_xor(p1, 16); p1 += __shfl_xor(p1, 32);
    p2 += __shfl_xor(p2, 16); p2 += __shfl_xor(p2, 32);
    if (lane < 8) {
      atomicAdd(&shift_acc[i * 24 + hh * 3 + 0], p0);
      atomicAdd(&shift_acc[i * 24 + hh * 3 + 1], p1);
      atomicAdd(&shift_acc[i * 24 + hh * 3 + 2], p2);
    }
  }
}

// ---------------------------------------------------------------------------
// h-output (phi_h MLP + residual) with x-output folded in (threads t<24).
// ---------------------------------------------------------------------------
__global__ __launch_bounds__(256) void k_hout(
    const float* __restrict__ x, const float* __restrict__ shift,
    const float* __restrict__ h, const float* __restrict__ mi,
    const float* __restrict__ Wh0, const float* __restrict__ bh0,
    const float* __restrict__ Wh1, const float* __restrict__ bh1,
    const float* __restrict__ Who, const float* __restrict__ bho,
    float* __restrict__ out_x, float* __restrict__ out_h)
{
  const int i = blockIdx.x, t = threadIdx.x;
  __shared__ float s_in[M + HD];
  __shared__ float s_b[M];
  if (t < 24) out_x[i * 24 + t] = x[i * 24 + t] + shift[i * 24 + t] * (1.f / 511.f);
  s_in[t] = mi[i * M + t];
  if (t < HD) s_in[M + t] = h[i * HD + t];
  __syncthreads();
  float acc = bh0[t];
  for (int k = 0; k < M + HD; ++k) acc = fmaf(s_in[k], Wh0[k * M + t], acc);
  s_b[t] = silu_f(acc);
  __syncthreads();
  float acc2 = bh1[t];
  for (int k = 0; k < M; ++k) acc2 = fmaf(s_b[k], Wh1[k * M + t], acc2);
  const float a1v = silu_f(acc2);
  __syncthreads();
  s_in[t] = a1v;
  __syncthreads();
  if (t < HD) {
    float o = bho[t];
    for (int k = 0; k < M; ++k) o = fmaf(s_in[k], Who[k * HD + t], o);
    out_h[i * HD + t] = h[i * HD + t] + o;
  }
}

// ---------------------------------------------------------------------------
extern "C" void kernel_launch(void* const* d_in, const int* in_sizes, int n_in,
                              void* d_out, int out_size, void* d_ws, size_t ws_size,
                              hipStream_t stream)
{
  const float* x    = (const float*)d_in[0];
  const float* h    = (const float*)d_in[1];
  const float* We0  = (const float*)d_in[2];
  const float* be0  = (const float*)d_in[3];
  const float* We1  = (const float*)d_in[4];
  const float* be1  = (const float*)d_in[5];
  const float* Winf = (const float*)d_in[6];
  const float* binf = (const float*)d_in[7];
  const float* Wx0  = (const float*)d_in[8];
  const float* bx0  = (const float*)d_in[9];
  const float* Wx1  = (const float*)d_in[10];
  const float* bx1  = (const float*)d_in[11];
  const float* Wxo  = (const float*)d_in[12];
  const float* bxo  = (const float*)d_in[13];
  const float* Wh0  = (const float*)d_in[14];
  const float* bh0  = (const float*)d_in[15];
  const float* Wh1  = (const float*)d_in[16];
  const float* bh1  = (const float*)d_in[17];
  const float* Who  = (const float*)d_in[18];
  const float* bho  = (const float*)d_in[19];

  float* out_x = (float*)d_out;                 // [512,8,3]
  float* out_h = out_x + N_NODES * NH * 3;      // [512,128]

  // ws layout (float units): mi[131072] | shift[12288] | P[131072] | Q[131072] | wsB(bf16)
  float* ws    = (float*)d_ws;
  float* mi    = ws;
  float* shift = ws + 131072;
  float* P     = ws + 143360;
  float* Q     = ws + 274432;
  unsigned short* wsB = (unsigned short*)(ws + 405504);

  k_pre<<<816 + N_NODES, 256, 0, stream>>>(
      x, h, We0, be0, We1, Wx0, Wx1, Wxo, wsB, P, Q, mi, shift);
  k_edge<<<dim3(N_NODES, N_NODES / JTILE), 256, 0, stream>>>(
      x, P, Q, be1, Winf, binf, bx0, bx1, bxo, wsB, mi, shift);
  k_hout<<<N_NODES, 256, 0, stream>>>(
      x, shift, h, mi, Wh0, bh0, Wh1, bh1, Who, bho, out_x, out_h);
}